// Round 8
// baseline (179.307 us; speedup 1.0000x reference)
//
#include <hip/hip_runtime.h>

typedef _Float16 f16x8 __attribute__((ext_vector_type(8)));
typedef float f32x4 __attribute__((ext_vector_type(4)));

#define EMB 768
#define LQ 128
#define LD 1024
#define NB 32

typedef const __attribute__((address_space(1))) char gas_char;
typedef __attribute__((address_space(3))) char las_char;

__device__ __forceinline__ void gload16(const void* g, void* l) {
    __builtin_amdgcn_global_load_lds((gas_char*)g, (las_char*)l, 16, 0, 0);
}

// 128B-row-stride tiles (BK=64 hw): 8 chunks of 16B, XOR row&7  (r2-proven)
#define SWZ(row, ch) ((row) * 64 + ((((ch) ^ ((row) & 7))) * 8))

// ---------- f32 -> f16, 8 elems/thread (W only) ----------
__global__ void cvt8_kernel(const float* __restrict__ in, _Float16* __restrict__ out, int n8) {
    int i = blockIdx.x * 256 + threadIdx.x;
    if (i >= n8) return;
    const float4 a = ((const float4*)in)[2 * i];
    const float4 b = ((const float4*)in)[2 * i + 1];
    f16x8 o;
    o[0] = (_Float16)a.x; o[1] = (_Float16)a.y; o[2] = (_Float16)a.z; o[3] = (_Float16)a.w;
    o[4] = (_Float16)b.x; o[5] = (_Float16)b.y; o[6] = (_Float16)b.z; o[7] = (_Float16)b.w;
    ((f16x8*)out)[i] = o;
}

// ---------- VT[b][e][q] = query_embed[b][q][e] (f16) ----------
__global__ void make_vt_kernel(const float* __restrict__ Q, _Float16* __restrict__ VT) {
    int i = blockIdx.x * 256 + threadIdx.x;
    if (i >= NB * EMB * LQ) return;
    int q = i % LQ;
    int e = (i / LQ) % EMB;
    int b = i / (LQ * EMB);
    VT[i] = (_Float16)Q[((size_t)b * LQ + q) * EMB + e];
}

// Stage a 128-row x 64-halfword f16 tile from f16 global (row stride 768 hw).
__device__ __forceinline__ void stage_tile(const _Float16* g, _Float16* l, int tid) {
#pragma unroll
    for (int i = 0; i < 4; ++i) {
        const int idx = i * 256 + tid;
        const int row = idx >> 3, ch = idx & 7;
        gload16(g + (size_t)row * EMB + ((ch ^ (row & 7)) * 8), l + (size_t)idx * 8);
    }
}

// ---------- projection GEMM, A read DIRECTLY as f32 (reg-staged), B(W16) via gload_lds ----
// OUT[m,h] = relu(A[m,:] . W[h,:] + bias[h]) in f16. 128x128 tile, 4 waves, dbuf LDS,
// __syncthreads fencing (r2-proven loop shape).
// Grid: 1D, nwg = nrowblk*6, XCD-chunked swizzle with COL-BLOCK FASTEST: each XCD
// runs one row-stripe's 6 col-blocks back-to-back, so the A-tile f32 re-reads (6x)
// hit that XCD's L2 and W becomes L2-resident (R7: row-fast order gave FETCH 178MB
// vs ~101MB ideal + exposed HBM latency every iter).
__global__ __launch_bounds__(256) void projd_kernel(
    const float* __restrict__ A, const _Float16* __restrict__ W16,
    const float* __restrict__ bias, _Float16* __restrict__ OUT) {
    __shared__ __align__(16) _Float16 smem[32768];  // 2 x (A 8192 | B 8192) halfwords
    const int tid = threadIdx.x, wave = tid >> 6, lane = tid & 63;
    const int wr = wave >> 1, wc = wave & 1;
    const int lr = lane & 15, lkg = lane >> 4;

    const int nwg = gridDim.x, cpx = nwg >> 3;   // nwg % 8 == 0 (1536 doc / 192 query)
    const int bid = blockIdx.x;
    const int swz = (bid & 7) * cpx + (bid >> 3);
    const int rowblk = swz / 6, colblk = swz - rowblk * 6;
    const int row0 = rowblk * 128, col0 = colblk * 128;

    const float* ga = A + (size_t)row0 * EMB;
    const _Float16* gb = W16 + (size_t)col0 * EMB;

    // A-stage source coordinates: 4 chunks/thread, chunk idx -> (row, swizzled col)
    int srow[4], scol[4];
#pragma unroll
    for (int i = 0; i < 4; ++i) {
        const int idx = i * 256 + tid;
        srow[i] = idx >> 3;
        scol[i] = ((idx & 7) ^ (srow[i] & 7)) * 8;
    }

    f32x4 acc[4][4];
#pragma unroll
    for (int m = 0; m < 4; ++m)
#pragma unroll
        for (int n = 0; n < 4; ++n) acc[m][n] = (f32x4){0.f, 0.f, 0.f, 0.f};

    // prologue: A0 load+cvt+write, B0 gload_lds
    float4 areg[4][2];
#pragma unroll
    for (int i = 0; i < 4; ++i) {
        const float* src = ga + (size_t)srow[i] * EMB + scol[i];
        areg[i][0] = *(const float4*)(src);
        areg[i][1] = *(const float4*)(src + 4);
    }
    stage_tile(gb, smem + 8192, tid);
#pragma unroll
    for (int i = 0; i < 4; ++i) {
        f16x8 v;
        v[0] = (_Float16)areg[i][0].x; v[1] = (_Float16)areg[i][0].y;
        v[2] = (_Float16)areg[i][0].z; v[3] = (_Float16)areg[i][0].w;
        v[4] = (_Float16)areg[i][1].x; v[5] = (_Float16)areg[i][1].y;
        v[6] = (_Float16)areg[i][1].z; v[7] = (_Float16)areg[i][1].w;
        *(f16x8*)(smem + (size_t)(i * 256 + tid) * 8) = v;
    }

    int cur = 0;
    for (int it = 0; it < 12; ++it) {
        __syncthreads();  // B(it) landed (vmcnt) + A(it) ds_writes visible (lgkm) + buf^1 free
        if (it < 11) {
            // issue next A-tile f32 loads NOW (latency hides under MFMA below)
#pragma unroll
            for (int i = 0; i < 4; ++i) {
                const float* src = ga + (size_t)srow[i] * EMB + (it + 1) * 64 + scol[i];
                areg[i][0] = *(const float4*)(src);
                areg[i][1] = *(const float4*)(src + 4);
            }
            stage_tile(gb + (it + 1) * 64, smem + (cur ^ 1) * 16384 + 8192, tid);
        }
        const _Float16* sA = smem + cur * 16384;
        const _Float16* sB = sA + 8192;
#pragma unroll
        for (int kk = 0; kk < 2; ++kk) {
            const int ch = kk * 4 + lkg;
            f16x8 af[4], bf[4];
#pragma unroll
            for (int m = 0; m < 4; ++m)
                af[m] = *(const f16x8*)(sA + SWZ(wr * 64 + m * 16 + lr, ch));
#pragma unroll
            for (int n = 0; n < 4; ++n)
                bf[n] = *(const f16x8*)(sB + SWZ(wc * 64 + n * 16 + lr, ch));
#pragma unroll
            for (int m = 0; m < 4; ++m)
#pragma unroll
                for (int n = 0; n < 4; ++n)
                    acc[m][n] = __builtin_amdgcn_mfma_f32_16x16x32_f16(af[m], bf[n], acc[m][n], 0, 0, 0);
        }
        if (it < 11) {
            // cvt + write next A-tile into the other buffer (readers of it are done:
            // they passed the barrier above; next barrier orders these writes)
            _Float16* dst = smem + (cur ^ 1) * 16384;
#pragma unroll
            for (int i = 0; i < 4; ++i) {
                f16x8 v;
                v[0] = (_Float16)areg[i][0].x; v[1] = (_Float16)areg[i][0].y;
                v[2] = (_Float16)areg[i][0].z; v[3] = (_Float16)areg[i][0].w;
                v[4] = (_Float16)areg[i][1].x; v[5] = (_Float16)areg[i][1].y;
                v[6] = (_Float16)areg[i][1].z; v[7] = (_Float16)areg[i][1].w;
                *(f16x8*)(dst + (size_t)(i * 256 + tid) * 8) = v;
            }
        }
        cur ^= 1;
    }

    const int crow = lkg * 4;
#pragma unroll
    for (int n = 0; n < 4; ++n) {
        const int gc = col0 + wc * 64 + n * 16 + lr;
        const float bv = bias[gc];
#pragma unroll
        for (int m = 0; m < 4; ++m) {
            const size_t gr = row0 + wr * 64 + m * 16 + crow;
#pragma unroll
            for (int r = 0; r < 4; ++r) {
                float v = acc[m][n][r] + bv;
                OUT[(gr + r) * EMB + gc] = (_Float16)(v > 0.f ? v : 0.f);
            }
        }
    }
}

// ---------- attention: 128 doc rows/block (r2-proven, verbatim) ----------
__global__ __launch_bounds__(256) void attn128_kernel(
    const _Float16* __restrict__ Do, const _Float16* __restrict__ Qo,
    const _Float16* __restrict__ VT, float* __restrict__ OUT) {
    __shared__ __align__(16) _Float16 smem[32768];  // dbuf staging; P[128][136] aliases after
    const int tid = threadIdx.x, wave = tid >> 6, lane = tid & 63;
    const int lr = lane & 15, lkg = lane >> 4;
    const int b = blockIdx.x, dblk = blockIdx.y;
    const _Float16* gd = Do + ((size_t)b * LD + dblk * 128) * EMB;
    const _Float16* gq = Qo + (size_t)b * LQ * EMB;

    f32x4 s[2][8];
#pragma unroll
    for (int m = 0; m < 2; ++m)
#pragma unroll
        for (int n = 0; n < 8; ++n) s[m][n] = (f32x4){0.f, 0.f, 0.f, 0.f};

    stage_tile(gd, smem, tid);
    stage_tile(gq, smem + 8192, tid);
    int cur = 0;
    for (int it = 0; it < 12; ++it) {
        __syncthreads();
        if (it < 11) {
            stage_tile(gd + (it + 1) * 64, smem + (cur ^ 1) * 16384, tid);
            stage_tile(gq + (it + 1) * 64, smem + (cur ^ 1) * 16384 + 8192, tid);
        }
        const _Float16* sD = smem + cur * 16384;
        const _Float16* sQ = sD + 8192;
#pragma unroll
        for (int kk = 0; kk < 2; ++kk) {
            const int ch = kk * 4 + lkg;
            f16x8 am[2];
#pragma unroll
            for (int m = 0; m < 2; ++m)
                am[m] = *(const f16x8*)(sD + SWZ(wave * 32 + m * 16 + lr, ch));
#pragma unroll
            for (int n = 0; n < 8; ++n) {
                const f16x8 bq = *(const f16x8*)(sQ + SWZ(n * 16 + lr, ch));
#pragma unroll
                for (int m = 0; m < 2; ++m)
                    s[m][n] = __builtin_amdgcn_mfma_f32_16x16x32_f16(am[m], bq, s[m][n], 0, 0, 0);
            }
        }
        cur ^= 1;
    }
    __syncthreads();  // all staging-buffer reads done before P overwrites smem

    _Float16 (*P)[136] = (_Float16 (*)[136])smem;  // pad 8: 272B stride -> 2-way (free)
    const int crow = lkg * 4;
#pragma unroll
    for (int m = 0; m < 2; ++m) {
#pragma unroll
        for (int r = 0; r < 4; ++r) {
            float mx = -1e30f;
#pragma unroll
            for (int n = 0; n < 8; ++n) mx = fmaxf(mx, s[m][n][r]);
#pragma unroll
            for (int off = 1; off < 16; off <<= 1) mx = fmaxf(mx, __shfl_xor(mx, off));
            float p[8], sum = 0.f;
#pragma unroll
            for (int n = 0; n < 8; ++n) { p[n] = __expf(s[m][n][r] - mx); sum += p[n]; }
#pragma unroll
            for (int off = 1; off < 16; off <<= 1) sum += __shfl_xor(sum, off);
            const float inv = 1.f / sum;
            const int row = wave * 32 + m * 16 + crow + r;
#pragma unroll
            for (int n = 0; n < 8; ++n) P[row][n * 16 + lr] = (_Float16)(p[n] * inv);
        }
    }
    __syncthreads();

    const _Float16* vtb = VT + (size_t)b * EMB * LQ;
#pragma unroll 1
    for (int nc = 0; nc < 6; ++nc) {
        f32x4 o[2][8];
#pragma unroll
        for (int m = 0; m < 2; ++m)
#pragma unroll
            for (int t = 0; t < 8; ++t) o[m][t] = (f32x4){0.f, 0.f, 0.f, 0.f};
#pragma unroll
        for (int ks = 0; ks < 4; ++ks) {
            f16x8 am[2];
#pragma unroll
            for (int m = 0; m < 2; ++m)
                am[m] = *(const f16x8*)(&P[wave * 32 + m * 16 + lr][ks * 32 + lkg * 8]);
#pragma unroll
            for (int t = 0; t < 8; ++t) {
                const f16x8 bv = *(const f16x8*)(vtb + (size_t)(nc * 128 + t * 16 + lr) * LQ + ks * 32 + lkg * 8);
#pragma unroll
                for (int m = 0; m < 2; ++m)
                    o[m][t] = __builtin_amdgcn_mfma_f32_16x16x32_f16(am[m], bv, o[m][t], 0, 0, 0);
            }
        }
#pragma unroll
        for (int t = 0; t < 8; ++t) {
#pragma unroll
            for (int m = 0; m < 2; ++m) {
                const size_t gr = (size_t)b * LD + dblk * 128 + wave * 32 + m * 16 + crow;
                const int e = nc * 128 + t * 16 + lr;
#pragma unroll
                for (int r = 0; r < 4; ++r)
                    OUT[(gr + r) * EMB + e] = o[m][t][r];
            }
        }
    }
}

extern "C" void kernel_launch(void* const* d_in, const int* in_sizes, int n_in,
                              void* d_out, int out_size, void* d_ws, size_t ws_size,
                              hipStream_t stream) {
    const float* doc   = (const float*)d_in[0];   // [32,1024,768]
    const float* query = (const float*)d_in[1];   // [32,128,768]
    const float* W     = (const float*)d_in[2];   // [768,768]
    const float* bias  = (const float*)d_in[3];   // [768]
    float* out = (float*)d_out;                   // [32,1024,768] f32

    const size_t nW  = (size_t)EMB * EMB;        // 589824
    const size_t nVT = (size_t)NB * EMB * LQ;    // 3145728
    const size_t nQo = (size_t)NB * LQ * EMB;    // 3145728
    const size_t nDo = (size_t)NB * LD * EMB;    // 25165824
    const size_t need = (nW + nVT + nQo + nDo) * sizeof(_Float16);  // ~64.1 MB (proven fits)
    if (ws_size < need) return;

    _Float16* W16 = (_Float16*)d_ws;
    _Float16* VT  = W16 + nW;
    _Float16* Qo  = VT + nVT;
    _Float16* Do  = Qo + nQo;

    cvt8_kernel<<<(int)(nW / 8 / 256), 256, 0, stream>>>(W, W16, (int)(nW / 8));
    make_vt_kernel<<<(int)(nVT / 256), 256, 0, stream>>>(query, VT);

    // projections read f32 activations directly; 1D grid, XCD-chunked col-fast swizzle
    projd_kernel<<<dim3(NB * LQ / 128 * 6), 256, 0, stream>>>(query, W16, bias, Qo);
    projd_kernel<<<dim3(NB * LD / 128 * 6), 256, 0, stream>>>(doc, W16, bias, Do);

    attn128_kernel<<<dim3(NB, LD / 128), 256, 0, stream>>>(Do, Qo, VT, out);
}

// Round 9
// 154.637 us; speedup vs baseline: 1.1595x; 1.1595x over previous
//
#include <hip/hip_runtime.h>

typedef _Float16 f16x8 __attribute__((ext_vector_type(8)));
typedef float f32x4 __attribute__((ext_vector_type(4)));

#define EMB 768
#define LQ 128
#define LD 1024
#define NB 32

typedef const __attribute__((address_space(1))) char gas_char;
typedef __attribute__((address_space(3))) char las_char;

__device__ __forceinline__ void gload16(const void* g, void* l) {
    __builtin_amdgcn_global_load_lds((gas_char*)g, (las_char*)l, 16, 0, 0);
}

// 128B-row tiles: 8 chunks of 16B, XOR row&7. 0 bank conflicts measured (R7/R8).
#define SWZ(row, ch) ((row) * 64 + ((((ch) ^ ((row) & 7))) * 8))

#define BAR() asm volatile("s_barrier" ::: "memory")
#define LGKM0() do { asm volatile("s_waitcnt lgkmcnt(0)" ::: "memory"); \
                     __builtin_amdgcn_sched_barrier(0); } while (0)
#define VMW(N) asm volatile("s_waitcnt vmcnt(" #N ")" ::: "memory")

// ---------- f32 -> f16, 8 elems/thread ----------
__global__ void cvt8_kernel(const float* __restrict__ in, _Float16* __restrict__ out, int n8) {
    int i = blockIdx.x * 256 + threadIdx.x;
    if (i >= n8) return;
    const float4 a = ((const float4*)in)[2 * i];
    const float4 b = ((const float4*)in)[2 * i + 1];
    f16x8 o;
    o[0] = (_Float16)a.x; o[1] = (_Float16)a.y; o[2] = (_Float16)a.z; o[3] = (_Float16)a.w;
    o[4] = (_Float16)b.x; o[5] = (_Float16)b.y; o[6] = (_Float16)b.z; o[7] = (_Float16)b.w;
    ((f16x8*)out)[i] = o;
}

// ---------- VT[b][e][q] = query_embed[b][q][e] (f16) ----------
__global__ void make_vt_kernel(const float* __restrict__ Q, _Float16* __restrict__ VT) {
    int i = blockIdx.x * 256 + threadIdx.x;
    if (i >= NB * EMB * LQ) return;
    int q = i % LQ;
    int e = (i / LQ) % EMB;
    int b = i / (LQ * EMB);
    VT[i] = (_Float16)Q[((size_t)b * LQ + q) * EMB + e];
}

// Stage a 128-row x 64-hw f16 tile (256-thread version, r2-proven).
__device__ __forceinline__ void stage_tile(const _Float16* g, _Float16* l, int tid) {
#pragma unroll
    for (int i = 0; i < 4; ++i) {
        const int idx = i * 256 + tid;
        const int row = idx >> 3, ch = idx & 7;
        gload16(g + (size_t)row * EMB + ((ch ^ (row & 7)) * 8), l + (size_t)idx * 8);
    }
}

// ---------- 256x256 8-phase projection GEMM (m201 template port, f16) ----------
// OUT[m,h] = relu(A[m,:].W[h,:]+bias[h]) f16. M=36864 (doc||query), N=768, K=768.
// 512 thr = 8 waves (wr 0-1 x wc 0-3), per-wave out 128x64. BK=64, 12 K-tiles,
// 6 iters x 2 K-tiles. LDS 128KB dynamic: [slot0|slot1] x [Ah0 Ah1 Bh0 Bh1] x 16KB.
// VMCNT LEDGER (4 gload16/stage-pair, per wave):
//   prologue: B0,A0,B1,A1 (16 out) -> vmcnt(8): kt0 landed, kt1 (8) in flight.
//   iter j: P3 stage B(kt+2)->slot0 [+4]; P4 stage A(kt+2) [+4] then vmcnt(4):
//     retires kt1-prev(8)+B(kt+2)(4), leaves A(kt+2) -> P5-P8's K-tile landed. ✓
//   P7 stage B(kt+3)->slot1; P8 stage A(kt+3) then vmcnt(4): leaves A(kt+3);
//     next iter's slot0 K-tile landed before P1'. ✓
//   region freedom: B-halves read P1,P2 -> stage at P3 (after P2 barrier);
//     A-halves read P1,P3 -> stage at P4. Same for P5-P8/slot1. ✓
//   tail j=5: no stages; vmcnt(0) at P4 drains kt11's A.
__global__ __launch_bounds__(512, 2) void proj8_kernel(
    const _Float16* __restrict__ A, const _Float16* __restrict__ W16,
    const float* __restrict__ bias, _Float16* __restrict__ OUT) {
    extern __shared__ _Float16 smem[];  // 65536 hw = 128 KB
    const int tid = threadIdx.x, wave = tid >> 6, lane = tid & 63;
    const int lr = lane & 15, lkg = lane >> 4;
    const int wr = wave >> 2, wc = wave & 3;

    // XCD swizzle, col-fastest (432 % 8 == 0): A-tile's 3 col-reuses adjacent
    const int nwg = gridDim.x, cpx = nwg >> 3;
    const int swz = (blockIdx.x & 7) * cpx + (blockIdx.x >> 3);
    const int rowblk = swz / 3, colblk = swz - rowblk * 3;
    const int row0 = rowblk * 256, col0 = colblk * 256;

    // per-thread staging coords (2 chunks per 128x64 half-tile)
    const int r0_ = tid >> 3, c0_ = (((tid & 7) ^ (r0_ & 7)) * 8);
    const int r1_ = (512 + tid) >> 3, c1_ = ((((512 + tid) & 7) ^ (r1_ & 7)) * 8);
    const int lo0 = tid * 8, lo1 = (512 + tid) * 8;

    const _Float16* gA0 = A + (size_t)row0 * EMB;          // A half0 origin
    const _Float16* gA1 = A + (size_t)(row0 + 128) * EMB;  // A half1
    const _Float16* gB0 = W16 + (size_t)col0 * EMB;
    const _Float16* gB1 = W16 + (size_t)(col0 + 128) * EMB;

#define STAGE_PAIR(g0, g1, kt, lbase) do { \
    const _Float16* s0_ = (g0) + (kt) * 64; const _Float16* s1_ = (g1) + (kt) * 64; \
    _Float16* d_ = (lbase); \
    gload16(s0_ + (size_t)r0_ * EMB + c0_, d_ + lo0); \
    gload16(s0_ + (size_t)r1_ * EMB + c1_, d_ + lo1); \
    gload16(s1_ + (size_t)r0_ * EMB + c0_, d_ + 8192 + lo0); \
    gload16(s1_ + (size_t)r1_ * EMB + c1_, d_ + 8192 + lo1); } while (0)

    f32x4 acc[8][4];
#pragma unroll
    for (int m = 0; m < 8; ++m)
#pragma unroll
        for (int n = 0; n < 4; ++n) acc[m][n] = (f32x4){0.f, 0.f, 0.f, 0.f};

    f16x8 aF[4][2], bF[4][2];
    const int bro = (wc & 1) * 64;  // B row offset within its half

#define READ_A(slot, MH) do { _Float16* ab_ = smem + (slot) * 32768 + wr * 8192; \
    _Pragma("unroll") for (int mm = 0; mm < 4; ++mm) _Pragma("unroll") for (int ks = 0; ks < 2; ++ks) \
        aF[mm][ks] = *(const f16x8*)(ab_ + SWZ(((MH) * 4 + mm) * 16 + lr, ks * 4 + lkg)); } while (0)
#define READ_B(slot, NH) do { _Float16* bb_ = smem + (slot) * 32768 + 16384 + (wc >> 1) * 8192; \
    _Pragma("unroll") for (int nn = 0; nn < 2; ++nn) _Pragma("unroll") for (int ks = 0; ks < 2; ++ks) \
        bF[(NH) * 2 + nn][ks] = *(const f16x8*)(bb_ + SWZ(bro + ((NH) * 2 + nn) * 16 + lr, ks * 4 + lkg)); } while (0)
#define MFMA_Q(MH, NH) do { __builtin_amdgcn_s_setprio(1); \
    _Pragma("unroll") for (int mm = 0; mm < 4; ++mm) _Pragma("unroll") for (int nn = 0; nn < 2; ++nn) \
    _Pragma("unroll") for (int ks = 0; ks < 2; ++ks) \
        acc[(MH) * 4 + mm][(NH) * 2 + nn] = __builtin_amdgcn_mfma_f32_16x16x32_f16( \
            aF[mm][ks], bF[(NH) * 2 + nn][ks], acc[(MH) * 4 + mm][(NH) * 2 + nn], 0, 0, 0); \
    __builtin_amdgcn_s_setprio(0); } while (0)

    // prologue: kt0 -> slot0, kt1 -> slot1 (B-pair then A-pair each)
    STAGE_PAIR(gB0, gB1, 0, smem + 16384);
    STAGE_PAIR(gA0, gA1, 0, smem);
    STAGE_PAIR(gB0, gB1, 1, smem + 32768 + 16384);
    STAGE_PAIR(gA0, gA1, 1, smem + 32768);
    VMW(8);
    BAR();

#pragma unroll 1
    for (int j = 0; j < 6; ++j) {
        const int kt2 = 2 * j + 2, kt3 = 2 * j + 3;
        // ---- K-tile 2j (slot 0) ----
        READ_B(0, 0); READ_B(0, 1); READ_A(0, 0);                 // P1: 12 reads
        BAR(); LGKM0(); MFMA_Q(0, 0); BAR();
        /* P2 (B n2-3 already read at P1 into bF[2..3]) */        // P2: 0 new reads
        BAR(); LGKM0(); MFMA_Q(0, 1); BAR();
        READ_A(0, 1);                                             // P3: 8 reads
        if (j < 5) STAGE_PAIR(gB0, gB1, kt2, smem + 16384);       // B free after P2
        BAR(); LGKM0(); MFMA_Q(1, 0); BAR();
        if (j < 5) { STAGE_PAIR(gA0, gA1, kt2, smem); VMW(4); }   // P4: A free after P3
        else       { VMW(0); }
        BAR(); LGKM0(); MFMA_Q(1, 1); BAR();
        // ---- K-tile 2j+1 (slot 1) ----
        READ_B(1, 0); READ_B(1, 1); READ_A(1, 0);                 // P5
        BAR(); LGKM0(); MFMA_Q(0, 0); BAR();
        BAR(); LGKM0(); MFMA_Q(0, 1); BAR();                      // P6
        READ_A(1, 1);                                             // P7
        if (j < 5) STAGE_PAIR(gB0, gB1, kt3, smem + 32768 + 16384);
        BAR(); LGKM0(); MFMA_Q(1, 0); BAR();
        if (j < 5) { STAGE_PAIR(gA0, gA1, kt3, smem + 32768); VMW(4); }  // P8
        BAR(); LGKM0(); MFMA_Q(1, 1); BAR();
    }

    // epilogue: bias + ReLU + f16 store
    const int crow = lkg * 4;
#pragma unroll
    for (int n = 0; n < 4; ++n) {
        const int gc = col0 + wc * 64 + n * 16 + lr;
        const float bv = bias[gc];
#pragma unroll
        for (int m = 0; m < 8; ++m) {
            const size_t gr = (size_t)row0 + wr * 128 + m * 16 + crow;
#pragma unroll
            for (int r = 0; r < 4; ++r) {
                float v = acc[m][n][r] + bv;
                OUT[(gr + r) * EMB + gc] = (_Float16)(v > 0.f ? v : 0.f);
            }
        }
    }
#undef STAGE_PAIR
#undef READ_A
#undef READ_B
#undef MFMA_Q
}

// ---------- attention: 128 doc rows/block (r2-proven, verbatim) ----------
__global__ __launch_bounds__(256) void attn128_kernel(
    const _Float16* __restrict__ Do, const _Float16* __restrict__ Qo,
    const _Float16* __restrict__ VT, float* __restrict__ OUT) {
    __shared__ __align__(16) _Float16 smem[32768];
    const int tid = threadIdx.x, wave = tid >> 6, lane = tid & 63;
    const int lr = lane & 15, lkg = lane >> 4;
    const int b = blockIdx.x, dblk = blockIdx.y;
    const _Float16* gd = Do + ((size_t)b * LD + dblk * 128) * EMB;
    const _Float16* gq = Qo + (size_t)b * LQ * EMB;

    f32x4 s[2][8];
#pragma unroll
    for (int m = 0; m < 2; ++m)
#pragma unroll
        for (int n = 0; n < 8; ++n) s[m][n] = (f32x4){0.f, 0.f, 0.f, 0.f};

    stage_tile(gd, smem, tid);
    stage_tile(gq, smem + 8192, tid);
    int cur = 0;
    for (int it = 0; it < 12; ++it) {
        __syncthreads();
        if (it < 11) {
            stage_tile(gd + (it + 1) * 64, smem + (cur ^ 1) * 16384, tid);
            stage_tile(gq + (it + 1) * 64, smem + (cur ^ 1) * 16384 + 8192, tid);
        }
        const _Float16* sD = smem + cur * 16384;
        const _Float16* sQ = sD + 8192;
#pragma unroll
        for (int kk = 0; kk < 2; ++kk) {
            const int ch = kk * 4 + lkg;
            f16x8 am[2];
#pragma unroll
            for (int m = 0; m < 2; ++m)
                am[m] = *(const f16x8*)(sD + SWZ(wave * 32 + m * 16 + lr, ch));
#pragma unroll
            for (int n = 0; n < 8; ++n) {
                const f16x8 bq = *(const f16x8*)(sQ + SWZ(n * 16 + lr, ch));
#pragma unroll
                for (int m = 0; m < 2; ++m)
                    s[m][n] = __builtin_amdgcn_mfma_f32_16x16x32_f16(am[m], bq, s[m][n], 0, 0, 0);
            }
        }
        cur ^= 1;
    }
    __syncthreads();

    _Float16 (*P)[136] = (_Float16 (*)[136])smem;
    const int crow = lkg * 4;
#pragma unroll
    for (int m = 0; m < 2; ++m) {
#pragma unroll
        for (int r = 0; r < 4; ++r) {
            float mx = -1e30f;
#pragma unroll
            for (int n = 0; n < 8; ++n) mx = fmaxf(mx, s[m][n][r]);
#pragma unroll
            for (int off = 1; off < 16; off <<= 1) mx = fmaxf(mx, __shfl_xor(mx, off));
            float p[8], sum = 0.f;
#pragma unroll
            for (int n = 0; n < 8; ++n) { p[n] = __expf(s[m][n][r] - mx); sum += p[n]; }
#pragma unroll
            for (int off = 1; off < 16; off <<= 1) sum += __shfl_xor(sum, off);
            const float inv = 1.f / sum;
            const int row = wave * 32 + m * 16 + crow + r;
#pragma unroll
            for (int n = 0; n < 8; ++n) P[row][n * 16 + lr] = (_Float16)(p[n] * inv);
        }
    }
    __syncthreads();

    const _Float16* vtb = VT + (size_t)b * EMB * LQ;
#pragma unroll 1
    for (int nc = 0; nc < 6; ++nc) {
        f32x4 o[2][8];
#pragma unroll
        for (int m = 0; m < 2; ++m)
#pragma unroll
            for (int t = 0; t < 8; ++t) o[m][t] = (f32x4){0.f, 0.f, 0.f, 0.f};
#pragma unroll
        for (int ks = 0; ks < 4; ++ks) {
            f16x8 am[2];
#pragma unroll
            for (int m = 0; m < 2; ++m)
                am[m] = *(const f16x8*)(&P[wave * 32 + m * 16 + lr][ks * 32 + lkg * 8]);
#pragma unroll
            for (int t = 0; t < 8; ++t) {
                const f16x8 bv = *(const f16x8*)(vtb + (size_t)(nc * 128 + t * 16 + lr) * LQ + ks * 32 + lkg * 8);
#pragma unroll
                for (int m = 0; m < 2; ++m)
                    o[m][t] = __builtin_amdgcn_mfma_f32_16x16x32_f16(am[m], bv, o[m][t], 0, 0, 0);
            }
        }
#pragma unroll
        for (int t = 0; t < 8; ++t) {
#pragma unroll
            for (int m = 0; m < 2; ++m) {
                const size_t gr = (size_t)b * LD + dblk * 128 + wave * 32 + m * 16 + crow;
                const int e = nc * 128 + t * 16 + lr;
#pragma unroll
                for (int r = 0; r < 4; ++r)
                    OUT[(gr + r) * EMB + e] = o[m][t][r];
            }
        }
    }
}

extern "C" void kernel_launch(void* const* d_in, const int* in_sizes, int n_in,
                              void* d_out, int out_size, void* d_ws, size_t ws_size,
                              hipStream_t stream) {
    const float* doc   = (const float*)d_in[0];   // [32,1024,768]
    const float* query = (const float*)d_in[1];   // [32,128,768]
    const float* W     = (const float*)d_in[2];   // [768,768]
    const float* bias  = (const float*)d_in[3];   // [768]
    float* out = (float*)d_out;                   // [32,1024,768] f32

    const size_t nW  = (size_t)EMB * EMB;        // 589824
    const size_t nVT = (size_t)NB * EMB * LQ;    // 3145728
    const size_t nDo = (size_t)NB * LD * EMB;    // 25165824
    const size_t nQo = (size_t)NB * LQ * EMB;    // 3145728
    const size_t need = (nW + nVT + nDo + nQo) * sizeof(_Float16);  // ~64.1 MB (proven fits)
    if (ws_size < need) return;

    _Float16* W16 = (_Float16*)d_ws;
    _Float16* VT  = W16 + nW;
    _Float16* Do  = VT + nVT;    // Do || Qo contiguous: single merged proj output
    _Float16* Qo  = Do + nDo;

    // f16 doc||query contiguous in d_out (dead until attn overwrites it)
    _Float16* doc16 = (_Float16*)d_out;
    _Float16* q16   = doc16 + nDo;

    cvt8_kernel<<<(int)(nDo / 8 / 256), 256, 0, stream>>>(doc, doc16, (int)(nDo / 8));
    cvt8_kernel<<<(int)(nQo / 8 / 256), 256, 0, stream>>>(query, q16, (int)(nQo / 8));
    cvt8_kernel<<<(int)(nW / 8 / 256), 256, 0, stream>>>(W, W16, (int)(nW / 8));
    make_vt_kernel<<<(int)(nVT / 256), 256, 0, stream>>>(query, VT);

    // merged projection: M = 36864 -> 144 rowblks x 3 colblks = 432 blocks, 128KB LDS
    hipFuncSetAttribute(reinterpret_cast<const void*>(&proj8_kernel),
                        hipFuncAttributeMaxDynamicSharedMemorySize, 131072);
    proj8_kernel<<<dim3(144 * 3), 512, 131072, stream>>>(doc16, W16, bias, Do);

    attn128_kernel<<<dim3(NB, LD / 128), 256, 0, stream>>>(Do, Qo, VT, out);
}